// Round 9
// baseline (1169.250 us; speedup 1.0000x reference)
//
#include <hip/hip_runtime.h>

#define F_IN 33
#define FP 36      // padded input cols for gcn gather (18 uints)
#define C 128      // F_OUT
#define GROWS 16   // rows per block in dense kernels

__device__ __forceinline__ unsigned short f2bf(float f) {
  unsigned u = __float_as_uint(f);
  unsigned r = (u + 0x7fff + ((u >> 16) & 1)) >> 16;   // RNE
  return (unsigned short)r;
}
__device__ __forceinline__ unsigned pack2(float lo, float hi) {
  return (unsigned)f2bf(lo) | ((unsigned)f2bf(hi) << 16);
}
__device__ __forceinline__ float bflo(unsigned u) { return __uint_as_float(u << 16); }
__device__ __forceinline__ float bfhi(unsigned u) { return __uint_as_float(u & 0xffff0000u); }

// ---- CSR build -------------------------------------------------------------

// histogram of dst only (deg computed later from CSR, no float atomics)
__global__ void count_kernel(const int* __restrict__ col, int* __restrict__ cnt, int E) {
  int e = blockIdx.x * blockDim.x + threadIdx.x;
  if (e < E) atomicAdd(&cnt[col[e]], 1);
}

__global__ void scan1_kernel(const int* __restrict__ cnt, int* __restrict__ out,
                             int* __restrict__ bsum, int n) {
  __shared__ int lds[256];
  int t = threadIdx.x;
  int base = blockIdx.x * 1024 + t * 4;
  int v0 = (base + 0 < n) ? cnt[base + 0] : 0;
  int v1 = (base + 1 < n) ? cnt[base + 1] : 0;
  int v2 = (base + 2 < n) ? cnt[base + 2] : 0;
  int v3 = (base + 3 < n) ? cnt[base + 3] : 0;
  int tot = v0 + v1 + v2 + v3;
  lds[t] = tot;
  __syncthreads();
  for (int o = 1; o < 256; o <<= 1) {
    int x = (t >= o) ? lds[t - o] : 0;
    __syncthreads();
    lds[t] += x;
    __syncthreads();
  }
  int excl = lds[t] - tot;
  if (t == 255) bsum[blockIdx.x] = lds[255];
  if (base + 0 < n) out[base + 0] = excl;
  if (base + 1 < n) out[base + 1] = excl + v0;
  if (base + 2 < n) out[base + 2] = excl + v0 + v1;
  if (base + 3 < n) out[base + 3] = excl + v0 + v1 + v2;
}

__global__ void scan2_kernel(int* __restrict__ bsum, int nb) {
  __shared__ int lds[256];
  int t = threadIdx.x;
  int v = (t < nb) ? bsum[t] : 0;
  lds[t] = v;
  __syncthreads();
  for (int o = 1; o < 256; o <<= 1) {
    int x = (t >= o) ? lds[t - o] : 0;
    __syncthreads();
    lds[t] += x;
    __syncthreads();
  }
  if (t < nb) bsum[t] = lds[t] - v;
}

__global__ void scan3_kernel(int* __restrict__ off, const int* __restrict__ bsum, int n) {
  int i = blockIdx.x * blockDim.x + threadIdx.x;
  if (i < n) off[i] += bsum[i >> 10];
}

// sedge[p] = {row, raw w}
__global__ void scatter_kernel(const int* __restrict__ row, const int* __restrict__ col,
                               const float* __restrict__ w, const int* __restrict__ off,
                               int* __restrict__ cur, int2* __restrict__ sedge, int E) {
  int e = blockIdx.x * blockDim.x + threadIdx.x;
  if (e < E) {
    int c = col[e];
    int p = off[c] + atomicAdd(&cur[c], 1);
    sedge[p] = make_int2(row[e], __float_as_int(w[e]));
  }
}

// deg[c] = sum of w over CSR segment; dinv = rsqrt(deg + 1)
__global__ __launch_bounds__(256) void deg_dinv_kernel(
    const int* __restrict__ off, const int2* __restrict__ sedge,
    float* __restrict__ dinv, int N) {
  int c = blockIdx.x * 4 + (threadIdx.x >> 6);
  if (c >= N) return;
  int l = threadIdx.x & 63;
  float s = 0.f;
  int p1 = off[c + 1];
  for (int p = off[c] + l; p < p1; p += 64) s += __int_as_float(sedge[p].y);
  #pragma unroll
  for (int o = 32; o > 0; o >>= 1) s += __shfl_xor(s, o);
  if (l == 0) dinv[c] = rsqrtf(s + 1.0f);
}

// ---- parameter prep --------------------------------------------------------

__global__ void prep_dots_kernel(const float* __restrict__ W1, const float* __restrict__ as1,
                                 const float* __restrict__ ad1, const float* __restrict__ W2,
                                 const float* __restrict__ as2, const float* __restrict__ ad2,
                                 float* __restrict__ attv) {
  int t = blockIdx.x * 256 + threadIdx.x;
  if (t >= 1024) return;
  int layer = t >> 9, rem = t & 511, sd = rem >> 8, rem2 = rem & 255;
  int h = rem2 >> 7, k = rem2 & 127;
  const float* W = layer ? W2 : W1;
  const float* att = sd ? (layer ? ad2 : ad1) : (layer ? as2 : as1);
  float s = 0.f;
  for (int c2 = 0; c2 < C; c2++) s += W[k * 2 * C + h * C + c2] * att[h * C + c2];
  attv[t] = s;
}

// Wp[(h*128+k)*128 + j] = W[k, h*128+j]
__global__ void prep_repack_kernel(const float* __restrict__ W1, const float* __restrict__ W2,
                                   float* __restrict__ Wp1, float* __restrict__ Wp2) {
  int t = blockIdx.x * 256 + threadIdx.x;   // 0..65535
  int layer = t >> 15, rem = t & 32767, hk = rem >> 7, j = rem & 127;
  int h = hk >> 7, k = hk & 127;
  const float* W = layer ? W2 : W1;
  float* Wp = layer ? Wp2 : Wp1;
  Wp[hk * C + j] = W[k * 2 * C + h * C + j];
}

// Wz = [fc1W ; fc2W]
__global__ void prep_wz_kernel(const float* __restrict__ fc1W, const float* __restrict__ fc2W,
                               float* __restrict__ Wz) {
  int t = blockIdx.x * 256 + threadIdx.x;
  if (t >= 32768) return;
  Wz[t] = (t < 16384) ? fc1W[t] : fc2W[t - 16384];
}

__global__ void convert_x_kernel(const float* __restrict__ x, unsigned* __restrict__ X36U, int N) {
  int t = blockIdx.x * blockDim.x + threadIdx.x;
  if (t >= N * (FP / 2)) return;
  int n = t / (FP / 2);
  int p = t - n * (FP / 2);
  int c0 = 2 * p, c1 = 2 * p + 1;
  float f0 = (c0 < F_IN) ? x[n * F_IN + c0] : 0.f;
  float f1 = (c1 < F_IN) ? x[n * F_IN + c1] : 0.f;
  X36U[t] = pack2(f0, f1);
}

// ---- GCN (aggregate-then-project) -----------------------------------------

__global__ __launch_bounds__(256) void gcn_agg33_kernel(
    const unsigned* __restrict__ X36U, const int* __restrict__ off,
    const int2* __restrict__ sedge, const float* __restrict__ dinv,
    float* __restrict__ Xagg, int N) {
  int c = blockIdx.x * 4 + (threadIdx.x >> 6);
  if (c >= N) return;
  int l = threadIdx.x & 63;
  bool act = l < FP / 2;   // 18 active gather lanes
  float dc = dinv[c];
  unsigned uc = act ? X36U[(unsigned)c * (FP / 2) + l] : 0u;
  float A0x = dc * bflo(uc), A0y = dc * bfhi(uc);
  float A1x = 0.f, A1y = 0.f, A2x = 0.f, A2y = 0.f, A3x = 0.f, A3y = 0.f;
  int p = off[c], p1 = off[c + 1];
  for (; p + 4 <= p1; p += 4) {
    int2 e0 = sedge[p + 0], e1 = sedge[p + 1], e2 = sedge[p + 2], e3 = sedge[p + 3];
    unsigned u0 = 0, u1 = 0, u2 = 0, u3 = 0;
    if (act) {
      u0 = X36U[(unsigned)e0.x * (FP / 2) + l];
      u1 = X36U[(unsigned)e1.x * (FP / 2) + l];
      u2 = X36U[(unsigned)e2.x * (FP / 2) + l];
      u3 = X36U[(unsigned)e3.x * (FP / 2) + l];
    }
    float w0 = dinv[e0.x] * __int_as_float(e0.y);
    float w1 = dinv[e1.x] * __int_as_float(e1.y);
    float w2 = dinv[e2.x] * __int_as_float(e2.y);
    float w3 = dinv[e3.x] * __int_as_float(e3.y);
    A0x += w0 * bflo(u0); A0y += w0 * bfhi(u0);
    A1x += w1 * bflo(u1); A1y += w1 * bfhi(u1);
    A2x += w2 * bflo(u2); A2y += w2 * bfhi(u2);
    A3x += w3 * bflo(u3); A3y += w3 * bfhi(u3);
  }
  for (; p < p1; p++) {
    int2 e0 = sedge[p];
    unsigned u0 = act ? X36U[(unsigned)e0.x * (FP / 2) + l] : 0u;
    float w0 = dinv[e0.x] * __int_as_float(e0.y);
    A0x += w0 * bflo(u0); A0y += w0 * bfhi(u0);
  }
  if (act) {
    float2 o;
    o.x = dc * (A0x + A1x + A2x + A3x);
    o.y = dc * (A0y + A1y + A2y + A3y);
    ((float2*)Xagg)[(unsigned)c * (FP / 2) + l] = o;
  }
}

// H = relu(Xagg @ W33 + b); Hb bf16; layer-1 score dots
__global__ void gemm36_kernel(const float* __restrict__ Xagg, const float* __restrict__ W,
                              const float* __restrict__ b, const float* __restrict__ wsv,
                              const float* __restrict__ wdv, float* __restrict__ H,
                              unsigned short* __restrict__ Hb, float* __restrict__ asrc,
                              float* __restrict__ adst, int N) {
  int n0 = blockIdx.x * GROWS;
  int j = threadIdx.x;   // 0..127
  __shared__ float xr[GROWS * FP];    // 2.3 KB
  __shared__ float xls[GROWS * 132];  // 8.4 KB
  {
    const float4* src = (const float4*)(Xagg + (size_t)n0 * FP);
    float4* dst = (float4*)xr;
    for (int i = j; i < GROWS * FP / 4; i += 128) dst[i] = src[i];  // N%16==0
  }
  __syncthreads();
  float acc[GROWS];
  #pragma unroll
  for (int r = 0; r < GROWS; r++) acc[r] = 0.f;
  #pragma unroll 3
  for (int k = 0; k < F_IN; k++) {
    float wv = W[k * C + j];
    #pragma unroll
    for (int r = 0; r < GROWS; r++) acc[r] += xr[r * FP + k] * wv;
  }
  #pragma unroll
  for (int r = 0; r < GROWS; r++) {
    int n = n0 + r;
    float v = fmaxf(acc[r] + b[j], 0.f);
    if (n < N) {
      H[(size_t)n * C + j] = v;
      Hb[(size_t)n * C + j] = f2bf(v);
    }
    xls[r * 132 + j] = v;
  }
  __syncthreads();
  int r = j >> 3, sub = j & 7;
  float sa0 = 0.f, sd0 = 0.f, sa1 = 0.f, sd1 = 0.f;
  for (int k = sub; k < C; k += 8) {
    float v = xls[r * 132 + k];
    sa0 += v * wsv[k];      sd0 += v * wdv[k];
    sa1 += v * wsv[C + k];  sd1 += v * wdv[C + k];
  }
  #pragma unroll
  for (int o = 4; o > 0; o >>= 1) {
    sa0 += __shfl_down(sa0, o); sd0 += __shfl_down(sd0, o);
    sa1 += __shfl_down(sa1, o); sd1 += __shfl_down(sd1, o);
  }
  int n = n0 + r;
  if (sub == 0 && n < N) {
    asrc[n * 2 + 0] = sa0; adst[n * 2 + 0] = sd0;
    asrc[n * 2 + 1] = sa1; adst[n * 2 + 1] = sd1;
  }
}

// ---- GAT edge softmax (no deg cap): alpha -> global ------------------------
__global__ __launch_bounds__(256) void att_kernel(
    const float* __restrict__ asrc, const float* __restrict__ adst,
    const int* __restrict__ off, const int2* __restrict__ sedge,
    float2* __restrict__ alphaA, float2* __restrict__ selfwA,
    float2* __restrict__ sarrA, int N) {
  int c = blockIdx.x * 4 + (threadIdx.x >> 6);
  if (c >= N) return;
  int l = threadIdx.x & 63;
  float2 adc = ((const float2*)adst)[c];
  float2 asc = ((const float2*)asrc)[c];
  int p0 = off[c], p1 = off[c + 1];
  float e00 = asc.x + adc.x; e00 = e00 > 0.f ? e00 : 0.2f * e00;
  float e01 = asc.y + adc.y; e01 = e01 > 0.f ? e01 : 0.2f * e01;
  float m0 = e00, m1 = e01;
  // sweep 1: gather scores, stash raw scores to alphaA, track max
  for (int p = p0 + l; p < p1; p += 64) {
    int r = sedge[p].x;
    float2 av = ((const float2*)asrc)[r];
    float e0 = av.x + adc.x; e0 = e0 > 0.f ? e0 : 0.2f * e0;
    float e1 = av.y + adc.y; e1 = e1 > 0.f ? e1 : 0.2f * e1;
    alphaA[p] = make_float2(e0, e1);
    m0 = fmaxf(m0, e0); m1 = fmaxf(m1, e1);
  }
  #pragma unroll
  for (int o = 32; o > 0; o >>= 1) {
    m0 = fmaxf(m0, __shfl_xor(m0, o));
    m1 = fmaxf(m1, __shfl_xor(m1, o));
  }
  // sweep 2: exp in place (own writes), accumulate sums
  float s0 = 0.f, s1 = 0.f;
  for (int p = p0 + l; p < p1; p += 64) {
    float2 sc = alphaA[p];
    float a0 = __expf(sc.x - m0), a1 = __expf(sc.y - m1);
    alphaA[p] = make_float2(a0, a1);
    s0 += a0; s1 += a1;
  }
  #pragma unroll
  for (int o = 32; o > 0; o >>= 1) { s0 += __shfl_xor(s0, o); s1 += __shfl_xor(s1, o); }
  float w0 = __expf(e00 - m0), w1 = __expf(e01 - m1);
  if (l == 0) {
    selfwA[c] = make_float2(w0, w1);
    sarrA[c]  = make_float2(s0 + w0, s1 + w1);
  }
}

// GAT aggregate, one 32-feature chunk per launch (table slice 3.2 MB -> L2).
// 1 wave/node; 4 edge-groups x 16 lanes; lane covers feature pair fp.
__global__ __launch_bounds__(256) void gat_pass_kernel(
    const unsigned* __restrict__ HbU, const float2* __restrict__ alphaA,
    const float2* __restrict__ selfwA, const float2* __restrict__ sarrA,
    const int* __restrict__ off, const int2* __restrict__ sedge,
    unsigned* __restrict__ AggU, int pass, int N) {
  int c = blockIdx.x * 4 + (threadIdx.x >> 6);
  if (c >= N) return;
  int l = threadIdx.x & 63;
  int g = l >> 4, lg = l & 15;
  int fp = 16 * pass + lg;          // feature-pair index in [0,64)
  int p0 = off[c], p1 = off[c + 1];
  float ax = 0.f, ay = 0.f, az = 0.f, aw = 0.f;   // h0(lo,hi), h1(lo,hi)
  float bx = 0.f, by = 0.f, bz = 0.f, bw = 0.f;
  int p = p0 + g;
  for (; p + 4 < p1; p += 8) {
    int r0 = sedge[p].x, r1 = sedge[p + 4].x;
    float2 al0 = alphaA[p], al1 = alphaA[p + 4];
    unsigned u0 = HbU[(size_t)r0 * 64 + fp];
    unsigned u1 = HbU[(size_t)r1 * 64 + fp];
    float x0 = bflo(u0), y0 = bfhi(u0);
    float x1 = bflo(u1), y1 = bfhi(u1);
    ax += al0.x * x0; ay += al0.x * y0; az += al0.y * x0; aw += al0.y * y0;
    bx += al1.x * x1; by += al1.x * y1; bz += al1.y * x1; bw += al1.y * y1;
  }
  for (; p < p1; p += 4) {
    int r0 = sedge[p].x;
    float2 al0 = alphaA[p];
    unsigned u0 = HbU[(size_t)r0 * 64 + fp];
    float x0 = bflo(u0), y0 = bfhi(u0);
    ax += al0.x * x0; ay += al0.x * y0; az += al0.y * x0; aw += al0.y * y0;
  }
  ax += bx; ay += by; az += bz; aw += bw;
  if (g == 0) {   // self loop
    float2 sw = selfwA[c];
    unsigned uc = HbU[(size_t)c * 64 + fp];
    float xc = bflo(uc), yc = bfhi(uc);
    ax += sw.x * xc; ay += sw.x * yc; az += sw.y * xc; aw += sw.y * yc;
  }
  // reduce across the 4 groups (lanes l, l^16, l^32 hold same fp)
  #pragma unroll
  for (int o = 16; o <= 32; o <<= 1) {
    ax += __shfl_xor(ax, o); ay += __shfl_xor(ay, o);
    az += __shfl_xor(az, o); aw += __shfl_xor(aw, o);
  }
  if (g == 0) {
    float2 sr = sarrA[c];
    float inv0 = 1.f / sr.x, inv1 = 1.f / sr.y;
    AggU[(size_t)c * 128 + fp]      = pack2(ax * inv0, ay * inv0);
    AggU[(size_t)c * 128 + 64 + fp] = pack2(az * inv1, aw * inv1);
  }
}

// XT = 0.5*(Agg @ Wp) + b (+relu); bf16 LDS staging, row-split waves
__global__ __launch_bounds__(128) void post_gemm_kernel(
    const unsigned* __restrict__ AggU, const float* __restrict__ Wp,
    const float* __restrict__ b, float* __restrict__ XT,
    unsigned short* __restrict__ XTb, int relu, int N) {
  __shared__ unsigned az[GROWS][128];   // 8 KB
  int n0 = blockIdx.x * GROWS;
  int t = threadIdx.x;
  {
    const uint4* src = (const uint4*)AggU;
    for (int i = t; i < GROWS * 32; i += 128) {
      int r = i >> 5, cch = i & 31;
      int n = n0 + r;
      uint4 v = (n < N) ? src[(size_t)n * 32 + cch] : make_uint4(0u, 0u, 0u, 0u);
      *(uint4*)&az[r][cch * 4] = v;
    }
  }
  __syncthreads();
  int w = t >> 6;
  int l = t & 63;
  float acc0[8], acc1[8];
  #pragma unroll
  for (int r = 0; r < 8; r++) { acc0[r] = 0.f; acc1[r] = 0.f; }
  for (int k8 = 0; k8 < 256; k8 += 8) {
    float wA[8], wB[8];
    #pragma unroll
    for (int q = 0; q < 8; q++) {
      wA[q] = Wp[(k8 + q) * C + l];
      wB[q] = Wp[(k8 + q) * C + l + 64];
    }
    #pragma unroll
    for (int r = 0; r < 8; r++) {
      uint4 u = *(const uint4*)&az[w * 8 + r][k8 >> 1];
      float v0 = bflo(u.x), v1 = bfhi(u.x), v2 = bflo(u.y), v3 = bfhi(u.y);
      float v4 = bflo(u.z), v5 = bfhi(u.z), v6 = bflo(u.w), v7 = bfhi(u.w);
      acc0[r] += v0*wA[0] + v1*wA[1] + v2*wA[2] + v3*wA[3]
               + v4*wA[4] + v5*wA[5] + v6*wA[6] + v7*wA[7];
      acc1[r] += v0*wB[0] + v1*wB[1] + v2*wB[2] + v3*wB[3]
               + v4*wB[4] + v5*wB[5] + v6*wB[6] + v7*wB[7];
    }
  }
  float bA = b[l], bB = b[l + 64];
  #pragma unroll
  for (int r = 0; r < 8; r++) {
    int n = n0 + w * 8 + r;
    if (n < N) {
      float vA = 0.5f * acc0[r] + bA;
      float vB = 0.5f * acc1[r] + bB;
      if (relu) { vA = fmaxf(vA, 0.f); vB = fmaxf(vB, 0.f); }
      XT[(size_t)n * C + l]      = vA;
      XT[(size_t)n * C + l + 64] = vB;
      XTb[(size_t)n * C + l]      = f2bf(vA);
      XTb[(size_t)n * C + l + 64] = f2bf(vB);
    }
  }
}

// gated blend: K=256 GEMM over [xt|x] bf16 vs Wz f32; exact f32 epilogue
__global__ __launch_bounds__(128) void blend_kernel(
    const unsigned* __restrict__ XTbU, const unsigned* __restrict__ XbU,
    const float* __restrict__ XTf, const float* __restrict__ Xf,
    const float* __restrict__ Wz, const float* __restrict__ fc1b,
    const float* __restrict__ fc2b, const float* __restrict__ pb,
    float* __restrict__ out, unsigned short* __restrict__ Hb2,
    const float* __restrict__ wsv, const float* __restrict__ wdv,
    float* __restrict__ asrc, float* __restrict__ adst, int dots, int N) {
  __shared__ unsigned az[GROWS][128];
  __shared__ float xls[GROWS * 132];
  int n0 = blockIdx.x * GROWS;
  int t = threadIdx.x;
  {
    const uint4* s1 = (const uint4*)XTbU;
    const uint4* s2 = (const uint4*)XbU;
    for (int i = t; i < GROWS * 32; i += 128) {
      int r = i >> 5, cch = i & 31;
      int n = n0 + r;
      uint4 v;
      if (n < N) v = (cch < 16) ? s1[(size_t)n * 16 + cch] : s2[(size_t)n * 16 + (cch - 16)];
      else v = make_uint4(0u, 0u, 0u, 0u);
      *(uint4*)&az[r][cch * 4] = v;
    }
  }
  __syncthreads();
  int w = t >> 6;
  int l = t & 63;
  float acc0[8], acc1[8];
  #pragma unroll
  for (int r = 0; r < 8; r++) { acc0[r] = 0.f; acc1[r] = 0.f; }
  for (int k8 = 0; k8 < 256; k8 += 8) {
    float wA[8], wB[8];
    #pragma unroll
    for (int q = 0; q < 8; q++) {
      wA[q] = Wz[(k8 + q) * C + l];
      wB[q] = Wz[(k8 + q) * C + l + 64];
    }
    #pragma unroll
    for (int r = 0; r < 8; r++) {
      uint4 u = *(const uint4*)&az[w * 8 + r][k8 >> 1];
      float v0 = bflo(u.x), v1 = bfhi(u.x), v2 = bflo(u.y), v3 = bfhi(u.y);
      float v4 = bflo(u.z), v5 = bfhi(u.z), v6 = bflo(u.w), v7 = bfhi(u.w);
      acc0[r] += v0*wA[0] + v1*wA[1] + v2*wA[2] + v3*wA[3]
               + v4*wA[4] + v5*wA[5] + v6*wA[6] + v7*wA[7];
      acc1[r] += v0*wB[0] + v1*wB[1] + v2*wB[2] + v3*wB[3]
               + v4*wB[4] + v5*wB[5] + v6*wB[6] + v7*wB[7];
    }
  }
  float bbA = fc1b[l] + fc2b[l] + pb[l];
  float bbB = fc1b[l + 64] + fc2b[l + 64] + pb[l + 64];
  #pragma unroll
  for (int r = 0; r < 8; r++) {
    int rr = w * 8 + r;
    int n = n0 + rr;
    if (n < N) {
      float xtA = XTf[(size_t)n * C + l],      xA = Xf[(size_t)n * C + l];
      float xtB = XTf[(size_t)n * C + l + 64], xB = Xf[(size_t)n * C + l + 64];
      float tA = acc0[r] + bbA, tB = acc1[r] + bbB;
      float zA = 1.f / (1.f + __expf(-tA));
      float zB = 1.f / (1.f + __expf(-tB));
      float oA = zA * xtA + (1.f - zA) * xA;
      float oB = zB * xtB + (1.f - zB) * xB;
      out[(size_t)n * C + l]      = oA;
      out[(size_t)n * C + l + 64] = oB;
      if (dots) {
        Hb2[(size_t)n * C + l]      = f2bf(oA);
        Hb2[(size_t)n * C + l + 64] = f2bf(oB);
      }
      xls[rr * 132 + l] = oA;
      xls[rr * 132 + l + 64] = oB;
    } else {
      xls[rr * 132 + l] = 0.f;
      xls[rr * 132 + l + 64] = 0.f;
    }
  }
  if (!dots) return;
  __syncthreads();
  int r = t >> 3, sub = t & 7;
  float sa0 = 0.f, sd0 = 0.f, sa1 = 0.f, sd1 = 0.f;
  for (int k = sub; k < C; k += 8) {
    float v = xls[r * 132 + k];
    sa0 += v * wsv[k];      sd0 += v * wdv[k];
    sa1 += v * wsv[C + k];  sd1 += v * wdv[C + k];
  }
  #pragma unroll
  for (int o = 4; o > 0; o >>= 1) {
    sa0 += __shfl_down(sa0, o); sd0 += __shfl_down(sd0, o);
    sa1 += __shfl_down(sa1, o); sd1 += __shfl_down(sd1, o);
  }
  int n = n0 + r;
  if (sub == 0 && n < N) {
    asrc[n * 2 + 0] = sa0; adst[n * 2 + 0] = sd0;
    asrc[n * 2 + 1] = sa1; adst[n * 2 + 1] = sd1;
  }
}

// ---- launch ----------------------------------------------------------------

extern "C" void kernel_launch(void* const* d_in, const int* in_sizes, int n_in,
                              void* d_out, int out_size, void* d_ws, size_t ws_size,
                              hipStream_t stream) {
  const float* x_in  = (const float*)d_in[0];
  const int*   ei    = (const int*)d_in[1];
  const float* ew    = (const float*)d_in[2];
  const float* gcn_W = (const float*)d_in[3];
  const float* gcn_b = (const float*)d_in[4];
  const float* g1_W  = (const float*)d_in[5];
  const float* g1_as = (const float*)d_in[6];
  const float* g1_ad = (const float*)d_in[7];
  const float* g1_b  = (const float*)d_in[8];
  const float* g2_W  = (const float*)d_in[9];
  const float* g2_as = (const float*)d_in[10];
  const float* g2_ad = (const float*)d_in[11];
  const float* g2_b  = (const float*)d_in[12];
  const float* fc1_W = (const float*)d_in[13];
  const float* fc1_b = (const float*)d_in[14];
  const float* fc2_W = (const float*)d_in[15];
  const float* fc2_b = (const float*)d_in[16];
  const float* pb    = (const float*)d_in[17];

  const int N = in_sizes[0] / F_IN;
  const int E = in_sizes[2];
  const int* row = ei;
  const int* col = ei + E;

  char* ws = (char*)d_ws;
  size_t o = 0;
  auto alloc = [&](size_t bytes) -> void* {
    void* p = ws + o;
    o += (bytes + 255) & ~(size_t)255;
    return p;
  };
  int*   cnt   = (int*)alloc((size_t)(N + 1) * 4);
  int*   cur   = (int*)alloc((size_t)N * 4);
  size_t zero_bytes = o;                     // cnt+cur at ws start
  int*   off   = (int*)alloc((size_t)(N + 1) * 4);
  float* dinv  = (float*)alloc((size_t)N * 4);
  int*   bsum  = (int*)alloc(256 * 4);
  int2*  sedge = (int2*)alloc((size_t)E * 8);
  float* attv  = (float*)alloc(1024 * 4);                 // ws1,wd1,ws2,wd2
  float* Wp1   = (float*)alloc((size_t)256 * C * 4);
  float* Wp2   = (float*)alloc((size_t)256 * C * 4);
  float* Wz    = (float*)alloc((size_t)256 * C * 4);
  float* asrc  = (float*)alloc((size_t)N * 2 * 4);
  float* adst  = (float*)alloc((size_t)N * 2 * 4);
  float2* selfwA = (float2*)alloc((size_t)N * 8);
  float2* sarrA  = (float2*)alloc((size_t)N * 8);
  unsigned* X36U = (unsigned*)alloc((size_t)N * (FP / 2) * 4);   // bf16 [N,36]
  float* Xagg  = (float*)alloc((size_t)N * FP * 4);
  float* H     = (float*)alloc((size_t)N * C * 4);        // gcn out
  unsigned short* Hb  = (unsigned short*)alloc((size_t)N * C * 2);
  unsigned* AggU = (unsigned*)alloc((size_t)N * 128 * 4); // bf16 [N,2,128]
  float* XT    = (float*)alloc((size_t)N * C * 4);        // gat out
  unsigned short* XTb = (unsigned short*)alloc((size_t)N * C * 2);
  float* H2    = (float*)alloc((size_t)N * C * 4);        // blend1 out
  unsigned short* Hb2 = (unsigned short*)alloc((size_t)N * C * 2);
  // alphaA (E float2 = 12.8 MB) aliases d_out (25.6 MB): last read (layer-2
  // gat_pass) precedes the only d_out write (final blend).
  float2* alphaA = (float2*)d_out;
  (void)ws_size; (void)n_in; (void)out_size;

  float* ws1 = attv + 0,   *wd1 = attv + 256;
  float* ws2 = attv + 512, *wd2 = attv + 768;

  hipMemsetAsync(d_ws, 0, zero_bytes, stream);

  const int tb = 256;
  const int nP = N + 1;
  const int nb = (nP + 1023) / 1024;
  const int nodeg = (N + 3) / 4;

  // parameter prep (input-only deps)
  prep_dots_kernel<<<4, 256, 0, stream>>>(g1_W, g1_as, g1_ad, g2_W, g2_as, g2_ad, attv);
  prep_repack_kernel<<<256, 256, 0, stream>>>(g1_W, g2_W, Wp1, Wp2);
  prep_wz_kernel<<<128, 256, 0, stream>>>(fc1_W, fc2_W, Wz);
  convert_x_kernel<<<(N * (FP / 2) + tb - 1) / tb, tb, 0, stream>>>(x_in, X36U, N);

  // CSR build (cnt atomics only; deg from CSR afterwards)
  count_kernel<<<(E + tb - 1) / tb, tb, 0, stream>>>(col, cnt, E);
  scan1_kernel<<<nb, 256, 0, stream>>>(cnt, off, bsum, nP);
  scan2_kernel<<<1, 256, 0, stream>>>(bsum, nb);
  scan3_kernel<<<(nP + tb - 1) / tb, tb, 0, stream>>>(off, bsum, nP);
  scatter_kernel<<<(E + tb - 1) / tb, tb, 0, stream>>>(row, col, ew, off, cur, sedge, E);
  deg_dinv_kernel<<<nodeg, 256, 0, stream>>>(off, sedge, dinv, N);

  // GCN: aggregate 33-dim inputs, then project (+relu, +layer1 score dots)
  gcn_agg33_kernel<<<nodeg, 256, 0, stream>>>(X36U, off, sedge, dinv, Xagg, N);
  gemm36_kernel<<<(N + GROWS - 1) / GROWS, C, 0, stream>>>(Xagg, gcn_W, gcn_b, ws1, wd1,
                                                           H, Hb, asrc, adst, N);

  // GAT layer 1: softmax, 4 feature-chunk aggregate passes, project, blend
  att_kernel<<<nodeg, 256, 0, stream>>>(asrc, adst, off, sedge, alphaA, selfwA, sarrA, N);
  for (int p = 0; p < 4; p++)
    gat_pass_kernel<<<nodeg, 256, 0, stream>>>((const unsigned*)Hb, alphaA, selfwA, sarrA,
                                               off, sedge, AggU, p, N);
  post_gemm_kernel<<<(N + GROWS - 1) / GROWS, C, 0, stream>>>(AggU, Wp1, g1_b, XT, XTb, 1, N);
  blend_kernel<<<(N + GROWS - 1) / GROWS, C, 0, stream>>>(
      (const unsigned*)XTb, (const unsigned*)Hb, XT, H, Wz, fc1_b, fc2_b, pb,
      H2, Hb2, ws2, wd2, asrc, adst, 1, N);

  // GAT layer 2 + final blend into d_out
  att_kernel<<<nodeg, 256, 0, stream>>>(asrc, adst, off, sedge, alphaA, selfwA, sarrA, N);
  for (int p = 0; p < 4; p++)
    gat_pass_kernel<<<nodeg, 256, 0, stream>>>((const unsigned*)Hb2, alphaA, selfwA, sarrA,
                                               off, sedge, AggU, p, N);
  post_gemm_kernel<<<(N + GROWS - 1) / GROWS, C, 0, stream>>>(AggU, Wp2, g2_b, XT, XTb, 0, N);
  blend_kernel<<<(N + GROWS - 1) / GROWS, C, 0, stream>>>(
      (const unsigned*)XTb, (const unsigned*)Hb2, XT, H2, Wz, fc1_b, fc2_b, pb,
      (float*)d_out, (unsigned short*)0, ws2, wd2, asrc, adst, 0, N);
}